// Round 4
// baseline (437.281 us; speedup 1.0000x reference)
//
#include <hip/hip_runtime.h>
#include <hip/hip_bf16.h>

// LSTM cell: B=4096, IN=1024, H=2048.
// R9: 32x32x16 MFMA GEMM. 256x256 tile, 8 waves (2Mx4N), per-wave 128x64 as
// 4x2 tiles of 32x32. BK=32, 4 LDS buffers, ONE 16-MFMA cluster per K-tile
// (2 barriers), counted vmcnt(8), rotation-swizzled LDS chunks (staging
// macros unchanged), rectangular XCD mapping, fused LSTM epilogue v2.

#define BATCH 4096
#define INW   1024
#define HID   2048
#define GK    3072   // HID + INW
#define GN    8192   // 4*HID

typedef __attribute__((ext_vector_type(8))) short short8;
typedef __attribute__((ext_vector_type(4))) float floatx4;
typedef __attribute__((ext_vector_type(16))) float floatx16;

__device__ __forceinline__ unsigned short f2bf(float f) {
    union { float f; unsigned u; } v; v.f = f;
    unsigned r = v.u + 0x7FFFu + ((v.u >> 16) & 1u);
    return (unsigned short)(r >> 16);
}
__device__ __forceinline__ float sigf(float x) {
    return 1.0f / (1.0f + __expf(-x));
}
__device__ __forceinline__ float tanhfast(float x) {
    float t = __expf(fminf(fmaxf(2.0f * x, -30.0f), 30.0f));
    return (t - 1.0f) / (t + 1.0f);
}

// ---- pack kernel: fp32 -> bf16; W rows gate-interleaved: Wb row 4h+g = W_g[h] ----
__global__ __launch_bounds__(256) void pack_all(const float4* __restrict__ ph,
                                                const float4* __restrict__ x,
                                                const float4* __restrict__ Wi,
                                                const float4* __restrict__ Wf,
                                                const float4* __restrict__ Wo,
                                                const float4* __restrict__ Wc,
                                                unsigned short* __restrict__ hx,
                                                unsigned short* __restrict__ Wb) {
    long i = (long)blockIdx.x * 256 + threadIdx.x;
    const float4* src;
    unsigned short* dst;
    if (i < 1048576L) {            // prev_h [4096,2048] -> hx[:, 0:2048]
        int r  = (int)(i >> 8);
        int c8 = (int)(i & 255);
        src = ph + 2 * i;
        dst = hx + (size_t)r * GK + (size_t)c8 * 8;
    } else if (i < 1572864L) {     // x [4096,1024] -> hx[:, 2048:3072]
        long j = i - 1048576L;
        int r  = (int)(j >> 7);
        int c8 = (int)(j & 127);
        src = x + 2 * j;
        dst = hx + (size_t)r * GK + HID + (size_t)c8 * 8;
    } else {                        // W_g row h -> Wb row 4h+g (gate-interleaved)
        long j = i - 1572864L;
        const float4* Wg;
        int g;
        if (j < 786432L)            { Wg = Wi; g = 0; }
        else if (j < 1572864L)      { Wg = Wf; g = 1; j -= 786432L; }
        else if (j < 2359296L)      { Wg = Wo; g = 2; j -= 1572864L; }
        else                        { Wg = Wc; g = 3; j -= 2359296L; }
        src = Wg + 2 * j;
        int h  = (int)(j / 384);          // GK/8 = 384 chunks per row
        int kc = (int)(j - (long)h * 384);
        dst = Wb + (size_t)(4 * h + g) * GK + (size_t)kc * 8;
    }
    float4 v0 = src[0];
    float4 v1 = src[1];
    unsigned short o[8];
    o[0] = f2bf(v0.x); o[1] = f2bf(v0.y); o[2] = f2bf(v0.z); o[3] = f2bf(v0.w);
    o[4] = f2bf(v1.x); o[5] = f2bf(v1.y); o[6] = f2bf(v1.z); o[7] = f2bf(v1.w);
    *(short8*)dst = *(const short8*)o;
}

__device__ __forceinline__ void gld16(const unsigned short* g, unsigned short* l) {
    __builtin_amdgcn_global_load_lds((const __attribute__((address_space(1))) unsigned int*)g,
                                     (__attribute__((address_space(3))) unsigned int*)l,
                                     16, 0, 0);
}

template<int VM> __device__ __forceinline__ void wait_vm() {
    if constexpr (VM == 8)      asm volatile("s_waitcnt vmcnt(8)" ::: "memory");
    else if constexpr (VM == 4) asm volatile("s_waitcnt vmcnt(4)" ::: "memory");
    else if constexpr (VM == 0) asm volatile("s_waitcnt vmcnt(0)" ::: "memory");
    // VM == -1: no wait (final iteration)
}

// ---- fused GEMM + LSTM epilogue, 32x32x16 MFMA ----
// gates[M=4096, N=8192] = hx * Wb^T, col n <-> (h = n>>2, gate = n&3).
// Per K-tile: 12 ds_read_b128 (8 A frags, 4 B frags) + 4 global_load_lds,
// barrier, lgkmcnt(0), 16x mfma_32x32x16 (whole K-tile in one cluster),
// counted vmcnt(8), barrier.
// A/B fragment layout (32x32x16): lane holds row lane&31, k = 8*(lane>>5)+j.
// C/D layout: col = lane&31, row = (reg&3) + 8*(reg>>2) + 4*(lane>>5) [m74/m101].
__global__ __launch_bounds__(512, 2) void gemm_fused(const unsigned short* __restrict__ A,
                                                     const unsigned short* __restrict__ Bt,
                                                     const float* __restrict__ prev_c,
                                                     float* __restrict__ out) {
    __shared__ unsigned short lds[65536];   // 128 KiB: A bufs [0,32768), B bufs [32768,65536)
    const int tid  = threadIdx.x;
    const int wave = tid >> 6;
    const int lane = tid & 63;

    // rectangular XCD mapping: XCD x owns M-tiles [4*(x&3),+4) x N-tiles [16*(x>>2),+16)
    const int bid = blockIdx.x;
    const int x = bid & 7, ii = bid >> 3;          // ii in 0..63
    const int mt = ((x & 3) << 2) + (ii & 3);      // 0..15
    const int nt = ((x >> 2) << 4) + (ii >> 2);    // 0..31
    const long row0 = (long)mt * 256;
    const long col0 = (long)nt * 256;

    const int wm = wave >> 2;   // 0..1 -> rows wm*128
    const int wn = wave & 3;    // 0..3 -> cols wn*64

    // staging source pointers (pre-swizzled chunk: LDS slot tid&3 holds global chunk c0)
    const int c0 = ((tid & 3) - ((tid >> 3) & 3)) & 3;
    const unsigned short* gA0 = A  + (row0 + (tid >> 2)) * GK + c0 * 8;
    const unsigned short* gB0 = Bt + (col0 + (tid >> 2)) * GK + c0 * 8;

#define STAGE_A(kt, b) do { \
        unsigned short* _d = &lds[(b) * 8192 + tid * 8]; \
        gld16(gA0 + (size_t)(kt) * 32, _d); \
        gld16(gA0 + 128 * GK + (size_t)(kt) * 32, _d + 4096); \
    } while (0)
#define STAGE_B(kt, b) do { \
        unsigned short* _d = &lds[32768 + (b) * 8192 + tid * 8]; \
        gld16(gB0 + (size_t)(kt) * 32, _d); \
        gld16(gB0 + 128 * GK + (size_t)(kt) * 32, _d + 4096); \
    } while (0)

    // fragment read offsets (ushort units); rotation swizzle slot = (c + (R>>1)) & 3.
    // Lane: fr32 = lane&31 (row-in-tile), hk = lane>>5 (k-half).
    // A frag (mi,kk): row = wm*128 + mi*32 + fr32, chunk c = kk*2 + hk.
    // (R>>1)&3 is mi/nj-independent since mi*32>>1 = mi*16 ≡ 0 mod 4.
    const int fr32 = lane & 31;
    const int hk   = lane >> 5;
    const int RA0  = wm * 128 + fr32;
    const int RB0  = wn * 64 + fr32;
    const int sA   = (RA0 >> 1) & 3;
    const int sB   = (RB0 >> 1) & 3;
    const int a_k0 = RA0 * 32 + (((hk)     + sA) & 3) * 8;   // kk=0
    const int a_k1 = RA0 * 32 + (((2 + hk) + sA) & 3) * 8;   // kk=1
    const int b_k0 = RB0 * 32 + (((hk)     + sB) & 3) * 8;
    const int b_k1 = RB0 * 32 + (((2 + hk) + sB) & 3) * 8;

    floatx16 acc[4][2];
    #pragma unroll
    for (int i = 0; i < 4; i++)
        #pragma unroll
        for (int j = 0; j < 2; j++)
            acc[i][j] = (floatx16)(0.0f);

    // prologue: stage tiles 0,1,2 (12 loads); vmcnt(8) drains tile 0
    STAGE_A(0, 0); STAGE_B(0, 0);
    STAGE_A(1, 1); STAGE_B(1, 1);
    STAGE_A(2, 2); STAGE_B(2, 2);
    asm volatile("s_waitcnt vmcnt(8)" ::: "memory");
    __builtin_amdgcn_s_barrier();

#define K_ITER(t, VMW, STG) do { \
        const unsigned short* bufA = &lds[((t) & 3) * 8192]; \
        const unsigned short* bufB = &lds[32768 + ((t) & 3) * 8192]; \
        short8 af0[4], af1[4], bf0[2], bf1[2]; \
        _Pragma("unroll") \
        for (int i = 0; i < 4; i++) { \
            af0[i] = *(const short8*)&bufA[a_k0 + i * 1024]; \
            af1[i] = *(const short8*)&bufA[a_k1 + i * 1024]; \
        } \
        _Pragma("unroll") \
        for (int j = 0; j < 2; j++) { \
            bf0[j] = *(const short8*)&bufB[b_k0 + j * 1024]; \
            bf1[j] = *(const short8*)&bufB[b_k1 + j * 1024]; \
        } \
        if (STG) { STAGE_A((t) + 3, ((t) + 3) & 3); STAGE_B((t) + 3, ((t) + 3) & 3); } \
        __builtin_amdgcn_s_barrier(); \
        asm volatile("s_waitcnt lgkmcnt(0)" ::: "memory"); \
        __builtin_amdgcn_sched_barrier(0); \
        __builtin_amdgcn_s_setprio(1); \
        _Pragma("unroll") \
        for (int i = 0; i < 4; i++) \
            _Pragma("unroll") \
            for (int j = 0; j < 2; j++) \
                acc[i][j] = __builtin_amdgcn_mfma_f32_32x32x16_bf16(af0[i], bf0[j], acc[i][j], 0, 0, 0); \
        _Pragma("unroll") \
        for (int i = 0; i < 4; i++) \
            _Pragma("unroll") \
            for (int j = 0; j < 2; j++) \
                acc[i][j] = __builtin_amdgcn_mfma_f32_32x32x16_bf16(af1[i], bf1[j], acc[i][j], 0, 0, 0); \
        __builtin_amdgcn_s_setprio(0); \
        wait_vm<VMW>(); \
        __builtin_amdgcn_s_barrier(); \
    } while (0)

    // main loop: 96 K-tiles of 32. t < 93 stages tile t+3 (last staged = 95).
    int t = 0;
    for (; t < 93; ++t) K_ITER(t, 8, true);
    K_ITER(93, 4, false);   // drain tile 94 (tile 95 stays in flight)
    K_ITER(94, 0, false);   // drain tile 95
    K_ITER(95, -1, false);

#undef K_ITER
#undef STAGE_A
#undef STAGE_B

    // ---- fused LSTM epilogue v2 (32x32 C layout) ----
    // acc[mi][nj] covers rows wm*128 + mi*32 + (r&3)+8*(r>>2)+4*(lane>>5),
    // cols wn*64 + nj*32 + (lane&31).  Stage raw fp32 gates to LDS [128][256]
    // in two row-half passes; columns gate-interleaved (col = 4*h + g) so the
    // combine reads (i,f,o,c) as one float4; prev_c / out fully coalesced.
    const long hbase = col0 >> 2;        // global h base of this block (64 h per block)
    float* gbuf = (float*)lds;           // [128][256] fp32

    #pragma unroll 1
    for (int pass = 0; pass < 2; ++pass) {
        __syncthreads();
        if (wm == pass) {
            #pragma unroll
            for (int mi = 0; mi < 4; mi++) {
                #pragma unroll
                for (int nj = 0; nj < 2; nj++) {
                    const int colb = wn * 64 + nj * 32 + fr32;
                    #pragma unroll
                    for (int r = 0; r < 16; r++) {
                        const int row_loc = mi * 32 + (r & 3) + 8 * (r >> 2) + 4 * hk;
                        gbuf[row_loc * 256 + colb] = acc[mi][nj][r];
                    }
                }
            }
        }
        __syncthreads();
        #pragma unroll 4
        for (int p = 0; p < 16; p++) {
            const int u   = p * 512 + tid;   // 0..8191
            const int row = u >> 6;          // 0..127 within this half
            const int h   = u & 63;
            float4 g4 = *(const float4*)&gbuf[row * 256 + h * 4];  // (i,f,o,c)
            const long grow = row0 + pass * 128 + row;
            const long ob   = grow * (long)HID + hbase + h;
            float pc = prev_c[ob];
            float iv = sigf(g4.x);
            float fv = sigf(g4.y);
            float ov = sigf(g4.z);
            float cv = tanhfast(g4.w);
            float nc = fv * pc + iv * cv;
            float nh = ov * tanhfast(nc);
            out[ob] = nh;
            out[(size_t)BATCH * HID + ob] = nc;
        }
    }
}

extern "C" void kernel_launch(void* const* d_in, const int* in_sizes, int n_in,
                              void* d_out, int out_size, void* d_ws, size_t ws_size,
                              hipStream_t stream) {
    const float* x   = (const float*)d_in[0];
    const float* ph  = (const float*)d_in[1];
    const float* pc  = (const float*)d_in[2];
    const float* Wi  = (const float*)d_in[3];
    const float* Wf  = (const float*)d_in[4];
    const float* Wo  = (const float*)d_in[5];
    const float* Wc  = (const float*)d_in[6];

    // workspace (bf16): hx [4096,3072] | Wb [8192,3072]  (~75 MB; gates never hit HBM)
    unsigned short* hx = (unsigned short*)d_ws;
    unsigned short* Wb = hx + (size_t)BATCH * GK;
    float* out = (float*)d_out;

    pack_all<<<18432, 256, 0, stream>>>((const float4*)ph, (const float4*)x,
                                        (const float4*)Wi, (const float4*)Wf,
                                        (const float4*)Wo, (const float4*)Wc,
                                        hx, Wb);

    gemm_fused<<<512, 512, 0, stream>>>(hx, Wb, pc, out);
}

// Round 5
// 409.934 us; speedup vs baseline: 1.0667x; 1.0667x over previous
//
#include <hip/hip_runtime.h>
#include <hip/hip_bf16.h>

// LSTM cell: B=4096, IN=1024, H=2048.
// R10: software-pipelined fragment registers. 16x16x32 MFMA (R8 addressing,
// conflict-free), 256x256 tile, 8 waves, BK=32 ring-4 LDS buffers, stage t+3
// during t. Per tile 2 phases; each phase ISSUES THE NEXT PHASE'S ds_reads
// BEFORE its MFMA cluster (ping-pong frag sets afM0/afM1, bfP/bfQ), so the
// LDS pipe (~1150 cyc/K-32/CU) runs under the MFMA pipe (~1240 cyc) instead
// of serializing with it. vmcnt(6) once per tile (never 0 in main loop),
// lgkm(4)/lgkm(8) counted. Rectangular XCD map + fused epilogue v2 (R8).

#define BATCH 4096
#define INW   1024
#define HID   2048
#define GK    3072   // HID + INW
#define GN    8192   // 4*HID

typedef __attribute__((ext_vector_type(8))) short short8;
typedef __attribute__((ext_vector_type(4))) float floatx4;

__device__ __forceinline__ unsigned short f2bf(float f) {
    union { float f; unsigned u; } v; v.f = f;
    unsigned r = v.u + 0x7FFFu + ((v.u >> 16) & 1u);
    return (unsigned short)(r >> 16);
}
__device__ __forceinline__ float sigf(float x) {
    return 1.0f / (1.0f + __expf(-x));
}
__device__ __forceinline__ float tanhfast(float x) {
    float t = __expf(fminf(fmaxf(2.0f * x, -30.0f), 30.0f));
    return (t - 1.0f) / (t + 1.0f);
}

// ---- pack kernel: fp32 -> bf16; W rows gate-interleaved: Wb row 4h+g = W_g[h] ----
__global__ __launch_bounds__(256) void pack_all(const float4* __restrict__ ph,
                                                const float4* __restrict__ x,
                                                const float4* __restrict__ Wi,
                                                const float4* __restrict__ Wf,
                                                const float4* __restrict__ Wo,
                                                const float4* __restrict__ Wc,
                                                unsigned short* __restrict__ hx,
                                                unsigned short* __restrict__ Wb) {
    long i = (long)blockIdx.x * 256 + threadIdx.x;
    const float4* src;
    unsigned short* dst;
    if (i < 1048576L) {            // prev_h [4096,2048] -> hx[:, 0:2048]
        int r  = (int)(i >> 8);
        int c8 = (int)(i & 255);
        src = ph + 2 * i;
        dst = hx + (size_t)r * GK + (size_t)c8 * 8;
    } else if (i < 1572864L) {     // x [4096,1024] -> hx[:, 2048:3072]
        long j = i - 1048576L;
        int r  = (int)(j >> 7);
        int c8 = (int)(j & 127);
        src = x + 2 * j;
        dst = hx + (size_t)r * GK + HID + (size_t)c8 * 8;
    } else {                        // W_g row h -> Wb row 4h+g (gate-interleaved)
        long j = i - 1572864L;
        const float4* Wg;
        int g;
        if (j < 786432L)            { Wg = Wi; g = 0; }
        else if (j < 1572864L)      { Wg = Wf; g = 1; j -= 786432L; }
        else if (j < 2359296L)      { Wg = Wo; g = 2; j -= 1572864L; }
        else                        { Wg = Wc; g = 3; j -= 2359296L; }
        src = Wg + 2 * j;
        int h  = (int)(j / 384);          // GK/8 = 384 chunks per row
        int kc = (int)(j - (long)h * 384);
        dst = Wb + (size_t)(4 * h + g) * GK + (size_t)kc * 8;
    }
    float4 v0 = src[0];
    float4 v1 = src[1];
    unsigned short o[8];
    o[0] = f2bf(v0.x); o[1] = f2bf(v0.y); o[2] = f2bf(v0.z); o[3] = f2bf(v0.w);
    o[4] = f2bf(v1.x); o[5] = f2bf(v1.y); o[6] = f2bf(v1.z); o[7] = f2bf(v1.w);
    *(short8*)dst = *(const short8*)o;
}

__device__ __forceinline__ void gld16(const unsigned short* g, unsigned short* l) {
    __builtin_amdgcn_global_load_lds((const __attribute__((address_space(1))) unsigned int*)g,
                                     (__attribute__((address_space(3))) unsigned int*)l,
                                     16, 0, 0);
}

template<int N> __device__ __forceinline__ void wait_vm() {
    if constexpr (N == 8)      asm volatile("s_waitcnt vmcnt(8)" ::: "memory");
    else if constexpr (N == 6) asm volatile("s_waitcnt vmcnt(6)" ::: "memory");
    else if constexpr (N == 4) asm volatile("s_waitcnt vmcnt(4)" ::: "memory");
    else if constexpr (N == 0) asm volatile("s_waitcnt vmcnt(0)" ::: "memory");
}
template<int N> __device__ __forceinline__ void wait_lgkm() {
    if constexpr (N == 8)      asm volatile("s_waitcnt lgkmcnt(8)" ::: "memory");
    else if constexpr (N == 4) asm volatile("s_waitcnt lgkmcnt(4)" ::: "memory");
    else if constexpr (N == 0) asm volatile("s_waitcnt lgkmcnt(0)" ::: "memory");
}
#define SBAR __builtin_amdgcn_sched_barrier(0)

// ---- fused GEMM + LSTM epilogue ----
// gates[M,N] = hx * Wb^T, col n <-> (h = n>>2, gate = n&3).
// Pipeline ledger (steady state, per wave):
//  lgkm queue: PH0 issues 4 (afM1), PH1 issues 8 (afM0,bfNXT).
//   wait@PH0 = lgkm(4): drains PH1(t-1)'s 8 (MFMA mh0 operands), leaves afM1.
//   wait@PH1 = lgkm(8): drains afM1 (MFMA mh1 operands), leaves the new 8.
//  vm queue: PH0 stages A(t+3) [2], PH1 stages B(t+3) [2].
//   wait@PH0 = vmcnt(6): outstanding {A,B(t+1), A,B(t+2), A(t+3)} = 10,
//   drains A,B(t+1) -> published by PH0's end barrier BEFORE PH1 reads buf t+1.
//  WAR: stage into buf (t-1)&3 happens after the barrier that follows
//   lgkm-completion of all buf(t-1) reads (>= 1 barrier separation).
__global__ __launch_bounds__(512, 2) void gemm_fused(const unsigned short* __restrict__ A,
                                                     const unsigned short* __restrict__ Bt,
                                                     const float* __restrict__ prev_c,
                                                     float* __restrict__ out) {
    __shared__ unsigned short lds[65536];   // 128 KiB: A bufs [0,32768), B bufs [32768,65536)
    const int tid  = threadIdx.x;
    const int wave = tid >> 6;
    const int lane = tid & 63;

    // rectangular XCD mapping: XCD x owns M-tiles [4*(x&3),+4) x N-tiles [16*(x>>2),+16)
    const int bid = blockIdx.x;
    const int x = bid & 7, ii = bid >> 3;          // ii in 0..63
    const int mt = ((x & 3) << 2) + (ii & 3);      // 0..15
    const int nt = ((x >> 2) << 4) + (ii >> 2);    // 0..31
    const long row0 = (long)mt * 256;
    const long col0 = (long)nt * 256;

    const int wm = wave >> 2;   // 0..1 -> rows wm*128
    const int wn = wave & 3;    // 0..3 -> cols wn*64

    // staging source pointers (pre-swizzled chunk: LDS slot tid&3 holds global chunk c0)
    const int c0 = ((tid & 3) - ((tid >> 3) & 3)) & 3;
    const unsigned short* gA0 = A  + (row0 + (tid >> 2)) * GK + c0 * 8;
    const unsigned short* gB0 = Bt + (col0 + (tid >> 2)) * GK + c0 * 8;

#define STAGE_A(kt, b) do { \
        unsigned short* _d = &lds[(b) * 8192 + tid * 8]; \
        gld16(gA0 + (size_t)(kt) * 32, _d); \
        gld16(gA0 + 128 * GK + (size_t)(kt) * 32, _d + 4096); \
    } while (0)
#define STAGE_B(kt, b) do { \
        unsigned short* _d = &lds[32768 + (b) * 8192 + tid * 8]; \
        gld16(gB0 + (size_t)(kt) * 32, _d); \
        gld16(gB0 + 128 * GK + (size_t)(kt) * 32, _d + 4096); \
    } while (0)

    // fragment read offsets (ushort units); rotation swizzle slot = (cq + (fr>>1)) & 3
    const int fr = lane & 15;
    const int cq = lane >> 4;                       // k-chunk 0..3 (BK=32)
    const int slot = ((cq + (fr >> 1)) & 3) << 3;
    const int aoff = (wm * 128 + fr) * 32 + slot;   // + mi*512; mh1 rows +64 -> +2048
    const int boff = (wn * 64 + fr) * 32 + slot;    // + nj*512

    floatx4 acc[8][4];
    #pragma unroll
    for (int i = 0; i < 8; i++)
        #pragma unroll
        for (int j = 0; j < 4; j++)
            acc[i][j] = (floatx4)(0.0f);

    short8 afM0[4], afM1[4], bfP[4], bfQ[4];

    // prologue: stage tiles 0,1,2; drain tile 0; preload afM0/bfP (PH1(-1) role)
    STAGE_A(0, 0); STAGE_B(0, 0);
    STAGE_A(1, 1); STAGE_B(1, 1);
    STAGE_A(2, 2); STAGE_B(2, 2);
    wait_vm<8>();
    __builtin_amdgcn_s_barrier();
    SBAR;
    #pragma unroll
    for (int i = 0; i < 4; i++) afM0[i] = *(const short8*)&lds[aoff + i * 512];
    #pragma unroll
    for (int j = 0; j < 4; j++) bfP[j]  = *(const short8*)&lds[32768 + boff + j * 512];
    SBAR;

    // PH0(t): issue afM1 <- A-mh1(t); stage A(t+3); vmcnt; lgkm(4); MFMA mh0; barrier
#define PH0(T, BCUR, VMW, STG) do { \
        const unsigned short* bufA = &lds[((T) & 3) * 8192]; \
        _Pragma("unroll") \
        for (int i = 0; i < 4; i++) afM1[i] = *(const short8*)&bufA[aoff + 2048 + i * 512]; \
        if (STG) { STAGE_A((T) + 3, ((T) + 3) & 3); } \
        SBAR; \
        wait_vm<VMW>(); \
        wait_lgkm<4>(); \
        SBAR; \
        __builtin_amdgcn_s_setprio(1); \
        _Pragma("unroll") \
        for (int i = 0; i < 4; i++) \
            _Pragma("unroll") \
            for (int j = 0; j < 4; j++) \
                acc[i][j] = __builtin_amdgcn_mfma_f32_16x16x32_bf16(afM0[i], BCUR[j], acc[i][j], 0, 0, 0); \
        __builtin_amdgcn_s_setprio(0); \
        SBAR; \
        __builtin_amdgcn_s_barrier(); \
        SBAR; \
    } while (0)

    // PH1(t): issue afM0 <- A-mh0(t+1), BNXT <- B(t+1); stage B(t+3); lgkm; MFMA mh1; barrier
#define PH1(T, BCUR, BNXT, STG, NEXT, LGK) do { \
        const unsigned short* bufA2 = &lds[(((T) + 1) & 3) * 8192]; \
        const unsigned short* bufB2 = &lds[32768 + (((T) + 1) & 3) * 8192]; \
        if (NEXT) { \
            _Pragma("unroll") \
            for (int i = 0; i < 4; i++) afM0[i] = *(const short8*)&bufA2[aoff + i * 512]; \
            _Pragma("unroll") \
            for (int j = 0; j < 4; j++) BNXT[j] = *(const short8*)&bufB2[boff + j * 512]; \
        } \
        if (STG) { STAGE_B((T) + 3, ((T) + 3) & 3); } \
        SBAR; \
        wait_lgkm<LGK>(); \
        SBAR; \
        __builtin_amdgcn_s_setprio(1); \
        _Pragma("unroll") \
        for (int i = 0; i < 4; i++) \
            _Pragma("unroll") \
            for (int j = 0; j < 4; j++) \
                acc[4 + i][j] = __builtin_amdgcn_mfma_f32_16x16x32_bf16(afM1[i], BCUR[j], acc[4 + i][j], 0, 0, 0); \
        __builtin_amdgcn_s_setprio(0); \
        SBAR; \
        __builtin_amdgcn_s_barrier(); \
        SBAR; \
    } while (0)

    // main loop: 96 K-tiles of 32; stages run through t=92 (last staged = 95)
    for (int t = 0; t < 92; t += 2) {
        PH0(t, bfP, 6, true);      PH1(t, bfP, bfQ, true, true, 8);
        PH0(t + 1, bfQ, 6, true);  PH1(t + 1, bfQ, bfP, true, true, 8);
    }
    PH0(92, bfP, 6, true);   PH1(92, bfP, bfQ, true, true, 8);
    PH0(93, bfQ, 4, false);  PH1(93, bfQ, bfP, false, true, 8);
    PH0(94, bfP, 0, false);  PH1(94, bfP, bfQ, false, true, 8);
    PH0(95, bfQ, 0, false);  PH1(95, bfQ, bfP, false, false, 0);

#undef PH0
#undef PH1
#undef STAGE_A
#undef STAGE_B

    // ---- fused LSTM epilogue v2 (16x16 C layout) ----
    // C/D: col = lane&15, row = (lane>>4)*4 + reg [m89-verified].
    // Stage raw fp32 gates to LDS [128][256] per row-half; columns are
    // gate-interleaved (col = 4*h + g) so combine reads (i,f,o,c) as one float4.
    const int cr = (lane >> 4) << 2;
    const int cc = lane & 15;
    const long hbase = col0 >> 2;        // global h base of this block (64 h per block)
    float* gbuf = (float*)lds;           // [128][256] fp32

    #pragma unroll 1
    for (int pass = 0; pass < 2; ++pass) {
        __syncthreads();
        if (wm == pass) {
            #pragma unroll
            for (int mi = 0; mi < 8; mi++) {
                #pragma unroll
                for (int nj = 0; nj < 4; nj++) {
                    const int colb = wn * 64 + nj * 16 + cc;
                    #pragma unroll
                    for (int r = 0; r < 4; r++)
                        gbuf[(mi * 16 + cr + r) * 256 + colb] = acc[mi][nj][r];
                }
            }
        }
        __syncthreads();
        #pragma unroll 4
        for (int p = 0; p < 16; p++) {
            const int u   = p * 512 + tid;   // 0..8191
            const int row = u >> 6;          // 0..127 within this half
            const int h   = u & 63;
            float4 g4 = *(const float4*)&gbuf[row * 256 + h * 4];  // (i,f,o,c)
            const long grow = row0 + pass * 128 + row;
            const long ob   = grow * (long)HID + hbase + h;
            float pc = prev_c[ob];
            float iv = sigf(g4.x);
            float fv = sigf(g4.y);
            float ov = sigf(g4.z);
            float cv = tanhfast(g4.w);
            float nc = fv * pc + iv * cv;
            float nh = ov * tanhfast(nc);
            out[ob] = nh;
            out[(size_t)BATCH * HID + ob] = nc;
        }
    }
}

extern "C" void kernel_launch(void* const* d_in, const int* in_sizes, int n_in,
                              void* d_out, int out_size, void* d_ws, size_t ws_size,
                              hipStream_t stream) {
    const float* x   = (const float*)d_in[0];
    const float* ph  = (const float*)d_in[1];
    const float* pc  = (const float*)d_in[2];
    const float* Wi  = (const float*)d_in[3];
    const float* Wf  = (const float*)d_in[4];
    const float* Wo  = (const float*)d_in[5];
    const float* Wc  = (const float*)d_in[6];

    // workspace (bf16): hx [4096,3072] | Wb [8192,3072]  (~75 MB; gates never hit HBM)
    unsigned short* hx = (unsigned short*)d_ws;
    unsigned short* Wb = hx + (size_t)BATCH * GK;
    float* out = (float*)d_out;

    pack_all<<<18432, 256, 0, stream>>>((const float4*)ph, (const float4*)x,
                                        (const float4*)Wi, (const float4*)Wf,
                                        (const float4*)Wo, (const float4*)Wc,
                                        hx, Wb);

    gemm_fused<<<512, 512, 0, stream>>>(hx, Wb, pc, out);
}